// Round 15
// baseline (79.788 us; speedup 1.0000x reference)
//
#include <hip/hip_runtime.h>

#define BB 8
#define CC 256
#define HH 96
#define WW 96
#define HWW (HH*WW)
#define NLOC 256        // local prototypes (MFMA path)
#define PPAD 257        // + global prototype
#define THRESH 0.95f
#define NORM_EPS 1e-4f

typedef __attribute__((ext_vector_type(8))) _Float16 f16x8;
typedef __attribute__((ext_vector_type(16))) float f32x16;

union H16 { _Float16 f; unsigned short u; };

// ---- fused kernel 0+1: mask pooling (8 blocks) + feature pooling (2048) ----
__global__ void k01(const float* __restrict__ sup_fts,
                    const float* __restrict__ sup_mask,
                    const float* __restrict__ true_bg,
                    float* __restrict__ protos,
                    float* __restrict__ validf,
                    float* __restrict__ masksum) {
    __shared__ float red[256];
    int blk = blockIdx.x;
    int t = threadIdx.x;
    if (blk < BB * CC) {
        int b = blk >> 8, c = blk & 255;
        int gy = t >> 4, gx = t & 15;
        const float* fb = sup_fts + ((size_t)b * CC + c) * HWW;
        const float* mb = sup_mask + (size_t)b * HWW;
        int base = gy * 6 * WW + gx * 6;
        float fs = 0.f, fm = 0.f;
        for (int r = 0; r < 6; ++r) {
            const float* rowf = fb + base + r * WW;
            const float* rowm = mb + base + r * WW;
#pragma unroll
            for (int h = 0; h < 3; ++h) {
                float2 v  = *(const float2*)(rowf + 2 * h);
                float2 mk = *(const float2*)(rowm + 2 * h);
                fs += v.x + v.y;
                fm = fmaf(v.x, mk.x, fm);
                fm = fmaf(v.y, mk.y, fm);
            }
        }
        protos[((size_t)b * PPAD + t) * CC + c] = fs * (1.f / 36.f);
        red[t] = fm;
        __syncthreads();
        for (int off = 128; off > 0; off >>= 1) {
            if (t < off) red[t] += red[t + off];
            __syncthreads();
        }
        if (t == 0) protos[((size_t)b * PPAD + 256) * CC + c] = red[0];
    } else {
        int b = blk - BB * CC;
        int gy = t >> 4, gx = t & 15;
        const float* mb = sup_mask + (size_t)b * HWW;
        const float* gb = true_bg  + (size_t)b * HWW;
        int base = gy * 6 * WW + gx * 6;
        float ms = 0.f, bs = 0.f;
        for (int r = 0; r < 6; ++r) {
            const float* rowm = mb + base + r * WW;
            const float* rowg = gb + base + r * WW;
#pragma unroll
            for (int h = 0; h < 3; ++h) {
                float2 mk = *(const float2*)(rowm + 2 * h);
                float2 bg2 = *(const float2*)(rowg + 2 * h);
                ms += mk.x + mk.y;
                bs += bg2.x + bg2.y;
            }
        }
        float mmean = ms * (1.f / 36.f);
        float bmean = bs * (1.f / 36.f);
        validf[b * PPAD + t] = (mmean > THRESH && bmean < 0.5f) ? 1.f : 0.f;
        if (t == 0) validf[b * PPAD + 256] = 1.f;
        red[t] = ms;
        __syncthreads();
        for (int off = 128; off > 0; off >>= 1) {
            if (t < off) red[t] += red[t + off];
            __syncthreads();
        }
        if (t == 0) masksum[b] = red[0];
    }
}

// ------- kernel 2: finish gproto + normalize + emit fp16 proto image --------
// Pimg layout (fp16): [B][16 kstep][2 khalf][8 tile][32 col][8 e]
__global__ void k2_norm(float* __restrict__ protos,
                        const float* __restrict__ masksum,
                        unsigned short* __restrict__ Pimg) {
    int bp = blockIdx.x;
    int b = bp / PPAD;
    int p = bp - b * PPAD;
    int t = threadIdx.x;            // channel
    float v = protos[((size_t)b * PPAD + p) * CC + t];
    if (p == 256) v = v / (masksum[b] + 1e-5f);
    __shared__ float red[256];
    red[t] = v * v;
    __syncthreads();
    for (int off = 128; off > 0; off >>= 1) {
        if (t < off) red[t] += red[t + off];
        __syncthreads();
    }
    float norm = sqrtf(red[0]);
    float vn = v / fmaxf(norm, NORM_EPS);
    protos[((size_t)b * PPAD + p) * CC + t] = vn;
    if (p < NLOC) {
        H16 h; h.f = (_Float16)vn;            // RNE, err 2^-11
        int kstep = t >> 4, khalf = (t >> 3) & 1, e = t & 7;
        int tile = p >> 5, col = p & 31;
        size_t idx = ((((size_t)b * 16 + kstep) * 2 + khalf) * 8 + tile) * 256
                     + col * 8 + e;
        Pimg[idx] = h.u;
    }
}

// ---------------- kernel 3: MFMA dists + masked softmax + weighted sum ------
// TILE-LEVEL pipeline (round-14 structure, slot-aliasing bug fixed):
// 768 blocks (exactly 3/CU), each runs 3 consecutive 32-px tiles. Tile i's
// marathon/epilogue overlaps tile i+1's q staging (issue 8 ks before convert).
// FIX vs r14: QCONV(j-4) runs BEFORE QISSUE(j) in the same step — j and j-4
// share the qv[j&3] register slot, so r14's issue-first order made the
// convert read the NEXT group's data (absmax 1.9e-2).
#define LBAR()  do {                                             \
        asm volatile("s_waitcnt lgkmcnt(0)" ::: "memory");       \
        __builtin_amdgcn_sched_barrier(0);                       \
        __builtin_amdgcn_s_barrier();                            \
        __builtin_amdgcn_sched_barrier(0);                       \
    } while (0)

__global__ __launch_bounds__(256, 4)
void k3_mfma(const float* __restrict__ qry,
             const unsigned short* __restrict__ Pimg,
             const float* __restrict__ protos_n,
             const float* __restrict__ validf,
             float* __restrict__ out) {
    __shared__ alignas(16) unsigned short Qf[2][8192];     // 2 x 16 KB dbuf
    __shared__ float red_n[2][8][32], red_g[2][8][32];
    __shared__ float rn_s[2][32], gd_s[2][32];
    __shared__ float S_l[4][32], N_l[4][32];

    int blk = blockIdx.x;
    int b = blk & 7;                  // batch <-> XCD affinity
    int tgrp = blk >> 3;              // 0..95
    int pxbase = tgrp * 96;           // 3 tiles of 32 px
    int t = threadIdx.x;              // 0..255
    int l = t & 63;
    int w = t >> 6;                   // wave 0..3
    int col = l & 31;
    int h = l >> 5;
    int spx = t & 31;                 // staging: pixel
    int cg  = t >> 5;                 // staging: channel group

    const float* qB = qry + (size_t)b * CC * HWW + spx;
    const float* gp = protos_n + ((size_t)b * PPAD + 256) * CC;
    const unsigned short* Pb = Pimg + (size_t)b * 65536;
    float* outb = out + (size_t)b * HWW + pxbase;

    float vfl0 = validf[b * PPAD + w * 64 + col];
    float vfl1 = validf[b * PPAD + w * 64 + 32 + col];

    // ---- prologue: stage tile 0 into Qf[0] (once per block) ----
    {
        float nrm = 0.f, gac = 0.f;
        const float* qb = qB + pxbase;
#pragma unroll
        for (int j = 0; j < 8; ++j) {
            int c0 = cg * 32 + j * 4;
            float v[4];
#pragma unroll
            for (int i = 0; i < 4; ++i) v[i] = qb[(size_t)(c0 + i) * HWW];
            unsigned int hh[4];
#pragma unroll
            for (int i = 0; i < 4; ++i) {
                H16 x; x.f = (_Float16)v[i];
                hh[i] = x.u;
                nrm = fmaf(v[i], v[i], nrm);
                gac = fmaf(v[i], gp[c0 + i], gac);
            }
            uint2 pk;
            pk.x = hh[0] | (hh[1] << 16); pk.y = hh[2] | (hh[3] << 16);
            *(uint2*)&Qf[0][(cg * 8 + j) * 128 + spx * 4] = pk;
        }
        red_n[0][cg][spx] = nrm;
        red_g[0][cg][spx] = gac;
    }

#pragma unroll
    for (int ti = 0; ti < 3; ++ti) {
        const int p = ti & 1;
        LBAR();                       // Qf[p], red[p] ready (from prev tile)
        if (t < 32) {
            float n2 = 0.f, gs = 0.f;
#pragma unroll
            for (int i = 0; i < 8; ++i) { n2 += red_n[p][i][t]; gs += red_g[p][i][t]; }
            float rn = 1.f / fmaxf(sqrtf(n2), NORM_EPS);
            rn_s[p][t] = rn;
            gd_s[p][t] = gs * rn;
        }
        LBAR();                       // rn_s[p] visible

        // ---- marathon(ti) with folded staging(ti+1) ----
        f32x16 acc[2];
#pragma unroll
        for (int i = 0; i < 16; ++i) { acc[0][i] = 0.f; acc[1][i] = 0.f; }
        f16x8 Bf[2][2];
        float qv[4][4], gpv[4][4];
        float nrm = 0.f, gac = 0.f;
        const float* qbn = qB + pxbase + (ti + 1) * 32;

#define LOADB(KS, BUF) { _Pragma("unroll")                                    \
        for (int tix = 0; tix < 2; ++tix)                                     \
            Bf[BUF][tix] = *(const f16x8*)(Pb +                               \
                ((((size_t)(KS) * 2 + h) * 8 + (w * 2 + tix)) * 32 + col) * 8); }

#define QISSUE(J) { int c0 = cg * 32 + (J) * 4;                               \
        _Pragma("unroll")                                                     \
        for (int i = 0; i < 4; ++i) {                                         \
            qv[(J) & 3][i]  = qbn[(size_t)(c0 + i) * HWW];                    \
            gpv[(J) & 3][i] = gp[c0 + i]; } }

#define QCONV(J) { unsigned int hh[4];                                        \
        _Pragma("unroll")                                                     \
        for (int i = 0; i < 4; ++i) {                                         \
            float v = qv[(J) & 3][i];                                         \
            H16 x; x.f = (_Float16)v; hh[i] = x.u;                            \
            nrm = fmaf(v, v, nrm);                                            \
            gac = fmaf(v, gpv[(J) & 3][i], gac); }                            \
        uint2 pk; pk.x = hh[0] | (hh[1] << 16); pk.y = hh[2] | (hh[3] << 16); \
        *(uint2*)&Qf[1 - p][(cg * 8 + (J)) * 128 + spx * 4] = pk; }

        LOADB(0, 0);
        LOADB(1, 1);
#pragma unroll
        for (int ks = 0; ks < 16; ++ks) {
            int kq0 = ks * 4 + h * 2;
            uint2 a0 = *(const uint2*)&Qf[p][kq0 * 128 + col * 4];
            uint2 a1 = *(const uint2*)&Qf[p][(kq0 + 1) * 128 + col * 4];
            union { f16x8 v; unsigned int u[4]; } QA;
            QA.u[0] = a0.x; QA.u[1] = a0.y; QA.u[2] = a1.x; QA.u[3] = a1.y;
#pragma unroll
            for (int tix = 0; tix < 2; ++tix)
                acc[tix] = __builtin_amdgcn_mfma_f32_32x32x16_f16(QA.v, Bf[ks & 1][tix], acc[tix], 0, 0, 0);
            if (ks + 2 < 16) LOADB(ks + 2, ks & 1);
            if (ti < 2 && (ks & 1) == 0) {
                if (ks >= 8) QCONV((ks >> 1) - 4);     // convert j-4 FIRST (reads slot)
                QISSUE(ks >> 1);                       // then issue j (overwrites slot)
            }
        }
        if (ti < 2) {
            QCONV(4); QCONV(5); QCONV(6); QCONV(7);    // tail converts
            red_n[1 - p][cg][spx] = nrm;
            red_g[1 - p][cg][spx] = gac;
        }
#undef LOADB
#undef QISSUE
#undef QCONV

        // ---- epilogue(ti): softmax over this wave's 64 protos ----
        // D-map (verified m74/m101): proto = w*64 + tix*32 + col;
        // row(px) = (r&3) + 8*(r>>2) + 4*h.
#pragma unroll
        for (int r = 0; r < 16; ++r) {
            int row = (r & 3) + 8 * (r >> 2) + 4 * h;
            float rnv = rn_s[p][row];
            float d0 = acc[0][r] * rnv;
            float d1 = acc[1][r] * rnv;
            float l0 = (vfl0 != 0.f) ? d0 : -1e30f;
            float l1 = (vfl1 != 0.f) ? d1 : -1e30f;
            float e0 = __expf(l0 - 1.1f);              // masked -> exactly 0
            float e1 = __expf(l1 - 1.1f);
            float s = e0 + e1;
            float nn = fmaf(e0, l0, e1 * l1);
#pragma unroll
            for (int m = 1; m < 32; m <<= 1) {
                s  += __shfl_xor(s, m);
                nn += __shfl_xor(nn, m);
            }
            if (col == 0) { S_l[w][row] = s; N_l[w][row] = nn; }
        }
        LBAR();                       // S_l visible
        if (t < 32) {
            float gdv = gd_s[p][t];
            float eg = __expf(gdv - 1.1f);             // global proto, once
            float S = eg, N = eg * gdv;
#pragma unroll
            for (int i = 0; i < 4; ++i) { S += S_l[i][t]; N += N_l[i][t]; }
            outb[ti * 32 + t] = N / S;
        }
    }
}

extern "C" void kernel_launch(void* const* d_in, const int* in_sizes, int n_in,
                              void* d_out, int out_size, void* d_ws, size_t ws_size,
                              hipStream_t stream) {
    const float* qry = (const float*)d_in[0];
    const float* sup = (const float*)d_in[1];
    const float* msk = (const float*)d_in[2];
    const float* bg  = (const float*)d_in[3];
    float* out = (float*)d_out;

    float* ws = (float*)d_ws;
    float* protos  = ws;                                   // [B][257][256] f32
    float* validf  = protos + (size_t)BB * PPAD * CC;      // [B][257]
    float* masksum = validf + (size_t)BB * PPAD;           // [B]
    unsigned short* Pimg = (unsigned short*)(masksum + BB); // [B][16][2][8][32][8] fp16

    hipLaunchKernelGGL(k01, dim3(BB * CC + BB), dim3(256), 0, stream,
                       sup, msk, bg, protos, validf, masksum);
    hipLaunchKernelGGL(k2_norm, dim3(BB * PPAD), dim3(256), 0, stream, protos, masksum, Pimg);
    hipLaunchKernelGGL(k3_mfma, dim3(BB * 96), dim3(256), 0, stream,
                       qry, Pimg, protos, validf, out);
}

// Round 17
// 74.311 us; speedup vs baseline: 1.0737x; 1.0737x over previous
//
#include <hip/hip_runtime.h>

#define BB 8
#define CC 256
#define HH 96
#define WW 96
#define HWW (HH*WW)
#define NLOC 256        // local prototypes (MFMA path)
#define PPAD 257        // + global prototype
#define THRESH 0.95f
#define NORM_EPS 1e-4f

typedef __attribute__((ext_vector_type(8))) _Float16 f16x8;
typedef __attribute__((ext_vector_type(16))) float f32x16;

union H16 { _Float16 f; unsigned short u; };

// ---- fused kernel 0+1: mask pooling (8 blocks) + feature pooling (2048) ----
__global__ void k01(const float* __restrict__ sup_fts,
                    const float* __restrict__ sup_mask,
                    const float* __restrict__ true_bg,
                    float* __restrict__ protos,
                    float* __restrict__ validf,
                    float* __restrict__ masksum) {
    __shared__ float red[256];
    int blk = blockIdx.x;
    int t = threadIdx.x;
    if (blk < BB * CC) {
        int b = blk >> 8, c = blk & 255;
        int gy = t >> 4, gx = t & 15;
        const float* fb = sup_fts + ((size_t)b * CC + c) * HWW;
        const float* mb = sup_mask + (size_t)b * HWW;
        int base = gy * 6 * WW + gx * 6;
        float fs = 0.f, fm = 0.f;
        for (int r = 0; r < 6; ++r) {
            const float* rowf = fb + base + r * WW;
            const float* rowm = mb + base + r * WW;
#pragma unroll
            for (int h = 0; h < 3; ++h) {
                float2 v  = *(const float2*)(rowf + 2 * h);
                float2 mk = *(const float2*)(rowm + 2 * h);
                fs += v.x + v.y;
                fm = fmaf(v.x, mk.x, fm);
                fm = fmaf(v.y, mk.y, fm);
            }
        }
        protos[((size_t)b * PPAD + t) * CC + c] = fs * (1.f / 36.f);
        red[t] = fm;
        __syncthreads();
        for (int off = 128; off > 0; off >>= 1) {
            if (t < off) red[t] += red[t + off];
            __syncthreads();
        }
        if (t == 0) protos[((size_t)b * PPAD + 256) * CC + c] = red[0];
    } else {
        int b = blk - BB * CC;
        int gy = t >> 4, gx = t & 15;
        const float* mb = sup_mask + (size_t)b * HWW;
        const float* gb = true_bg  + (size_t)b * HWW;
        int base = gy * 6 * WW + gx * 6;
        float ms = 0.f, bs = 0.f;
        for (int r = 0; r < 6; ++r) {
            const float* rowm = mb + base + r * WW;
            const float* rowg = gb + base + r * WW;
#pragma unroll
            for (int h = 0; h < 3; ++h) {
                float2 mk = *(const float2*)(rowm + 2 * h);
                float2 bg2 = *(const float2*)(rowg + 2 * h);
                ms += mk.x + mk.y;
                bs += bg2.x + bg2.y;
            }
        }
        float mmean = ms * (1.f / 36.f);
        float bmean = bs * (1.f / 36.f);
        validf[b * PPAD + t] = (mmean > THRESH && bmean < 0.5f) ? 1.f : 0.f;
        if (t == 0) validf[b * PPAD + 256] = 1.f;
        red[t] = ms;
        __syncthreads();
        for (int off = 128; off > 0; off >>= 1) {
            if (t < off) red[t] += red[t + off];
            __syncthreads();
        }
        if (t == 0) masksum[b] = red[0];
    }
}

// ------- kernel 2: finish gproto + normalize + emit fp16 proto image --------
// Pimg layout (fp16): [B][16 kstep][2 khalf][8 tile][32 col][8 e]
__global__ void k2_norm(float* __restrict__ protos,
                        const float* __restrict__ masksum,
                        unsigned short* __restrict__ Pimg) {
    int bp = blockIdx.x;
    int b = bp / PPAD;
    int p = bp - b * PPAD;
    int t = threadIdx.x;            // channel
    float v = protos[((size_t)b * PPAD + p) * CC + t];
    if (p == 256) v = v / (masksum[b] + 1e-5f);
    __shared__ float red[256];
    red[t] = v * v;
    __syncthreads();
    for (int off = 128; off > 0; off >>= 1) {
        if (t < off) red[t] += red[t + off];
        __syncthreads();
    }
    float norm = sqrtf(red[0]);
    float vn = v / fmaxf(norm, NORM_EPS);
    protos[((size_t)b * PPAD + p) * CC + t] = vn;
    if (p < NLOC) {
        H16 h; h.f = (_Float16)vn;            // RNE, err 2^-11
        int kstep = t >> 4, khalf = (t >> 3) & 1, e = t & 7;
        int tile = p >> 5, col = p & 31;
        size_t idx = ((((size_t)b * 16 + kstep) * 2 + khalf) * 8 + tile) * 256
                     + col * 8 + e;
        Pimg[idx] = h.u;
    }
}

// ------- kernel 2q: DEDICATED q transpose+convert -> MFMA-ready image -------
// Reads q channel-major (coalesced 256B/instr, 64 independent loads/thread).
// Emits Qimg [B][288 tile][64 kq][32 px][4 ch] fp16 == k3's LDS layout, so
// k3 stages with a LINEAR global_load_lds copy. Also precomputes per-pixel
// rnorm and gd in fp32 (r13 math).
// FIX vs r16: write-out loop must cover ALL 4096 uint2 entries of T
// (r < 16, not r < 8) — r16 left kq 32..63 (channels 128..255) unwritten,
// k3 read 0xAA poison for the upper half of every dot (absmax 1.5e-2).
__global__ __launch_bounds__(256, 4)
void k2q(const float* __restrict__ qry,
         const float* __restrict__ protos_n,
         unsigned short* __restrict__ Qimg,
         float* __restrict__ rns,
         float* __restrict__ gds) {
    __shared__ alignas(16) unsigned short T[64 * 64 * 4];   // [kq][px64][4] = 32 KB
    __shared__ float gpl[256];
    __shared__ float rn4[4][64], rg4[4][64];

    int blk = blockIdx.x;
    int b = blk / 144;
    int tp = blk - b * 144;          // tile-pair 0..143
    int px0 = tp * 64;
    int t = threadIdx.x;
    int px = t & 63;
    int cq = t >> 6;                 // channel quarter (64 ch)

    const float* gp = protos_n + ((size_t)b * PPAD + 256) * CC;
    gpl[t] = gp[t];
    __syncthreads();

    const float* qb = qry + (size_t)b * CC * HWW + px0 + px;
    float nrm = 0.f, gac = 0.f;
#pragma unroll
    for (int j = 0; j < 16; ++j) {   // 4 channels per j
        int c0 = cq * 64 + j * 4;
        unsigned int hh[4];
#pragma unroll
        for (int i = 0; i < 4; ++i) {
            float v = qb[(size_t)(c0 + i) * HWW];
            H16 x; x.f = (_Float16)v;          // RNE
            hh[i] = x.u;
            nrm = fmaf(v, v, nrm);
            gac = fmaf(v, gpl[c0 + i], gac);
        }
        uint2 pk;
        pk.x = hh[0] | (hh[1] << 16); pk.y = hh[2] | (hh[3] << 16);
        int kq = cq * 16 + j;
        *(uint2*)&T[(kq * 64 + px) * 4] = pk;  // px*8B -> 2-way max (free)
    }
    rn4[cq][px] = nrm;
    rg4[cq][px] = gac;
    __syncthreads();
    if (t < 64) {
        float n2 = rn4[0][t] + rn4[1][t] + rn4[2][t] + rn4[3][t];
        float gs = rg4[0][t] + rg4[1][t] + rg4[2][t] + rg4[3][t];
        float rn = 1.f / fmaxf(sqrtf(n2), NORM_EPS);
        rns[(size_t)b * HWW + px0 + t] = rn;
        gds[(size_t)b * HWW + px0 + t] = gs * rn;
    }

    // write out both 16KB tiles: [tile][kq][px32][4] — ALL 4096 uint2 entries
    unsigned short* Qo = Qimg + ((size_t)b * 288 + (size_t)tp * 2) * 8192;
#pragma unroll
    for (int r = 0; r < 16; ++r) {
        int F = r * 256 + t;                   // uint2 index over [kq][px64]
        int kq = F >> 6, pxx = F & 63;
        uint2 v = *(const uint2*)&T[(kq * 64 + pxx) * 4];
        int tile = pxx >> 5, pl = pxx & 31;
        *(uint2*)&Qo[(size_t)tile * 8192 + (kq * 32 + pl) * 4] = v;
    }
}

// ---------------- kernel 3: MFMA dists + masked softmax + weighted sum ------
// r13 structure with staging replaced by a LINEAR 16KB global_load_lds copy
// of the pre-transposed Qimg tile (zero VALU, zero regs), rnorm/gd loaded
// precomputed, and the B stream deepened to 4 buffers. Marathon + epilogue
// byte-equivalent to r13 (verified D-map, conflicts=0 layout).
__global__ __launch_bounds__(256, 4)
void k3_mfma(const unsigned short* __restrict__ Qimg,
             const unsigned short* __restrict__ Pimg,
             const float* __restrict__ rns,
             const float* __restrict__ gds,
             const float* __restrict__ validf,
             float* __restrict__ out) {
    __shared__ alignas(16) unsigned short Qf[8192];        // [kq][px32][4] = 16 KB
    __shared__ float rn_s[32], gd_s[32];
    __shared__ float S_l[4][32], N_l[4][32];

    int blk = blockIdx.x;
    int b = blk & 7;                  // batch <-> XCD affinity
    int tile = blk >> 3;              // 0..287
    int px0 = tile * 32;
    int t = threadIdx.x;              // 0..255
    int l = t & 63;
    int w = t >> 6;                   // wave 0..3
    int col = l & 31;
    int h = l >> 5;

    const unsigned short* Qt = Qimg + ((size_t)b * 288 + tile) * 8192;
    const unsigned short* Pb = Pimg + (size_t)b * 65536;

    // ---- staging: linear 16KB copy via global_load_lds (4 x 16B/thread) ----
    {
        const char* src = (const char*)Qt + t * 16;
        char* dst = (char*)Qf + (t >> 6) * 1024;   // wave-uniform; HW adds lane*16
#pragma unroll
        for (int i = 0; i < 4; ++i)
            __builtin_amdgcn_global_load_lds((const void*)(src + i * 4096),
                                             (void*)(dst + i * 4096), 16, 0, 0);
    }
    if (t < 32) {
        rn_s[t] = rns[(size_t)b * HWW + px0 + t];
        gd_s[t] = gds[(size_t)b * HWW + px0 + t];
    }
    __syncthreads();                  // drains staging — B issued after

    // ---- B stream: 4-buf lookahead (loop's only VMEM) ----
    f32x16 acc[2];
#pragma unroll
    for (int i = 0; i < 16; ++i) { acc[0][i] = 0.f; acc[1][i] = 0.f; }
    f16x8 Bf[4][2];

#define LOADB(KS, BUF) { _Pragma("unroll")                                    \
        for (int tix = 0; tix < 2; ++tix)                                     \
            Bf[BUF][tix] = *(const f16x8*)(Pb +                               \
                ((((size_t)(KS) * 2 + h) * 8 + (w * 2 + tix)) * 32 + col) * 8); }

    LOADB(0, 0); LOADB(1, 1); LOADB(2, 2); LOADB(3, 3);

    // ---- marathon: 16 ks x {1 A-frag LDS read, 2 MFMA} ----
#pragma unroll
    for (int ks = 0; ks < 16; ++ks) {
        int kq0 = ks * 4 + h * 2;
        uint2 a0 = *(const uint2*)&Qf[(kq0 * 32 + col) * 4];
        uint2 a1 = *(const uint2*)&Qf[((kq0 + 1) * 32 + col) * 4];
        union { f16x8 v; unsigned int u[4]; } QA;
        QA.u[0] = a0.x; QA.u[1] = a0.y; QA.u[2] = a1.x; QA.u[3] = a1.y;
#pragma unroll
        for (int tix = 0; tix < 2; ++tix)
            acc[tix] = __builtin_amdgcn_mfma_f32_32x32x16_f16(QA.v, Bf[ks & 3][tix], acc[tix], 0, 0, 0);
        if (ks + 4 < 16) LOADB(ks + 4, ks & 3);
    }
#undef LOADB

    // ---- softmax epilogue (r13-verified) ----
    // D-map (m74/m101): proto = w*64 + tix*32 + col; row(px) = (r&3)+8*(r>>2)+4*h.
    float vf0 = validf[b * PPAD + w * 64 + col];
    float vf1 = validf[b * PPAD + w * 64 + 32 + col];
#pragma unroll
    for (int r = 0; r < 16; ++r) {
        int row = (r & 3) + 8 * (r >> 2) + 4 * h;
        float rnv = rn_s[row];
        float d0 = acc[0][r] * rnv;
        float d1 = acc[1][r] * rnv;
        float l0 = (vf0 != 0.f) ? d0 : -1e30f;
        float l1 = (vf1 != 0.f) ? d1 : -1e30f;
        float e0 = __expf(l0 - 1.1f);             // masked -> exactly 0
        float e1 = __expf(l1 - 1.1f);
        float s = e0 + e1;
        float nn = fmaf(e0, l0, e1 * l1);
#pragma unroll
        for (int m = 1; m < 32; m <<= 1) {        // reduce over 32 proto-cols
            s  += __shfl_xor(s, m);
            nn += __shfl_xor(nn, m);
        }
        if (col == 0) { S_l[w][row] = s; N_l[w][row] = nn; }
    }
    __syncthreads();

    if (t < 32) {
        float gdv = gd_s[t];
        float eg = __expf(gdv - 1.1f);            // global proto, exactly once
        float S = eg, N = eg * gdv;
#pragma unroll
        for (int i = 0; i < 4; ++i) { S += S_l[i][t]; N += N_l[i][t]; }
        out[(size_t)b * HWW + px0 + t] = N / S;
    }
}

extern "C" void kernel_launch(void* const* d_in, const int* in_sizes, int n_in,
                              void* d_out, int out_size, void* d_ws, size_t ws_size,
                              hipStream_t stream) {
    const float* qry = (const float*)d_in[0];
    const float* sup = (const float*)d_in[1];
    const float* msk = (const float*)d_in[2];
    const float* bg  = (const float*)d_in[3];
    float* out = (float*)d_out;

    float* ws = (float*)d_ws;
    float* protos  = ws;                                    // [B][257][256] f32
    float* validf  = protos + (size_t)BB * PPAD * CC;       // [B][257]
    float* masksum = validf + (size_t)BB * PPAD;            // [B]
    float* rns     = masksum + BB;                          // [B][9216]
    float* gds     = rns + (size_t)BB * HWW;                // [B][9216]
    unsigned short* Pimg = (unsigned short*)(gds + (size_t)BB * HWW); // 1 MB
    unsigned short* Qimg = Pimg + (size_t)BB * 65536;       // [B][288][8192] 37.75 MB

    hipLaunchKernelGGL(k01, dim3(BB * CC + BB), dim3(256), 0, stream,
                       sup, msk, bg, protos, validf, masksum);
    hipLaunchKernelGGL(k2_norm, dim3(BB * PPAD), dim3(256), 0, stream, protos, masksum, Pimg);
    hipLaunchKernelGGL(k2q, dim3(BB * 144), dim3(256), 0, stream,
                       qry, protos, Qimg, rns, gds);
    hipLaunchKernelGGL(k3_mfma, dim3(BB * (HWW / 32)), dim3(256), 0, stream,
                       Qimg, Pimg, rns, gds, validf, out);
}